// Round 1
// baseline (4078.622 us; speedup 1.0000x reference)
//
#include <hip/hip_runtime.h>
#include <hip/hip_bf16.h>

typedef __bf16 bf16_t;
typedef __bf16 bf16x8 __attribute__((ext_vector_type(8)));
typedef float f32x4 __attribute__((ext_vector_type(4)));

#define S_ 2048
#define D_ 4096
#define H_ 32
#define KVH_ 8
#define DH_ 128
#define HID_ 11008

// ---------------------------------------------------------------- RMSNorm ----
__global__ __launch_bounds__(256) void rmsnorm_kernel(
    const float* __restrict__ x, const float* __restrict__ w,
    bf16_t* __restrict__ out) {
  int row = blockIdx.x;
  const float* xr = x + (size_t)row * D_;
  float ss = 0.f;
  #pragma unroll
  for (int it = 0; it < 4; ++it) {
    int i = threadIdx.x * 4 + it * 1024;
    float4 v = *(const float4*)(xr + i);
    ss += v.x * v.x + v.y * v.y + v.z * v.z + v.w * v.w;
  }
  #pragma unroll
  for (int off = 32; off; off >>= 1) ss += __shfl_xor(ss, off);
  __shared__ float s4[4];
  if ((threadIdx.x & 63) == 0) s4[threadIdx.x >> 6] = ss;
  __syncthreads();
  float tot = s4[0] + s4[1] + s4[2] + s4[3];
  float rinv = rsqrtf(tot / (float)D_ + 1e-5f);
  bf16_t* orow = out + (size_t)row * D_;
  #pragma unroll
  for (int it = 0; it < 4; ++it) {
    int i = threadIdx.x * 4 + it * 1024;
    float4 v = *(const float4*)(xr + i);
    orow[i + 0] = (bf16_t)(v.x * rinv * w[i + 0]);
    orow[i + 1] = (bf16_t)(v.y * rinv * w[i + 1]);
    orow[i + 2] = (bf16_t)(v.z * rinv * w[i + 2]);
    orow[i + 3] = (bf16_t)(v.w * rinv * w[i + 3]);
  }
}

// ------------------------------------------------------------- RoPE table ----
__global__ __launch_bounds__(256) void rope_table_kernel(
    const int* __restrict__ pos_ids, float* __restrict__ cos_t,
    float* __restrict__ sin_t) {
  int idx = blockIdx.x * 256 + threadIdx.x;  // S_*64
  int s = idx >> 6, i = idx & 63;
  float pos = (float)pos_ids[s];
  // inv_freq = 10000^(-2i/128) = exp2(-(i/64)*log2(10000))
  float inv_freq = exp2f(-(float)i * (13.287712379549449f / 64.0f));
  float ang = pos * inv_freq;
  cos_t[idx] = cosf(ang);
  sin_t[idx] = sinf(ang);
}

// ------------------------------------------------------------- RoPE apply ----
__global__ __launch_bounds__(256) void rope_apply_kernel(
    const bf16_t* __restrict__ in, bf16_t* __restrict__ out,
    const float* __restrict__ cos_t, const float* __restrict__ sin_t,
    int nheads, int total) {
  int idx = blockIdx.x * 256 + threadIdx.x;  // over S*nheads*64 pairs
  if (idx >= total) return;
  int i = idx & 63;
  int tmp = idx >> 6;           // s*nheads + h
  int s = tmp / nheads;
  size_t base = (size_t)tmp * 128 + 2 * i;
  float x1 = (float)in[base], x2 = (float)in[base + 1];
  float c = cos_t[s * 64 + i], sn = sin_t[s * 64 + i];
  out[base]     = (bf16_t)(x1 * c - x2 * sn);
  out[base + 1] = (bf16_t)(x1 * sn + x2 * c);
}

// ------------------------------------------------------------------ GEMM -----
// C[M][N] = A[M][K](bf16) @ W[K][N](f32, converted to bf16 in staging)
// MODE 1: f32 out += residual R ; MODE 2: bf16 out
template <int MODE>
__global__ __launch_bounds__(256, 2) void gemm_kernel(
    const bf16_t* __restrict__ A, const float* __restrict__ W,
    const float* __restrict__ R, void* __restrict__ Cout, int M, int N, int K) {
  __shared__ __align__(16) bf16_t As[128][40];
  __shared__ __align__(16) bf16_t Bs[128][40];  // Bs[n][k]
  int tid = threadIdx.x;
  int lane = tid & 63, wid = tid >> 6;
  int wr = wid >> 1, wc = wid & 1;
  int g = lane >> 4, fr = lane & 15;
  int row0 = blockIdx.x * 128, col0 = blockIdx.y * 128;
  f32x4 acc[4][4] = {};

  int ar = tid >> 1;
  int ak = (tid & 1) * 16;
  const bf16_t* aptr = A + (size_t)(row0 + ar) * K + ak;

  for (int k0 = 0; k0 < K; k0 += 32) {
    __syncthreads();
    bf16x8 a0 = *(const bf16x8*)(aptr + k0);
    bf16x8 a1 = *(const bf16x8*)(aptr + k0 + 8);
    *(bf16x8*)&As[ar][ak] = a0;
    *(bf16x8*)&As[ar][ak + 8] = a1;
    #pragma unroll
    for (int i = 0; i < 4; ++i) {
      int flat = i * 1024 + tid * 4;
      int kk = flat >> 7, nn = flat & 127;
      float4 wv = *(const float4*)(W + (size_t)(k0 + kk) * N + col0 + nn);
      Bs[nn + 0][kk] = (bf16_t)wv.x;
      Bs[nn + 1][kk] = (bf16_t)wv.y;
      Bs[nn + 2][kk] = (bf16_t)wv.z;
      Bs[nn + 3][kk] = (bf16_t)wv.w;
    }
    __syncthreads();
    bf16x8 af[4], bfv[4];
    #pragma unroll
    for (int m = 0; m < 4; ++m)
      af[m] = *(const bf16x8*)&As[wr * 64 + m * 16 + fr][g * 8];
    #pragma unroll
    for (int n = 0; n < 4; ++n)
      bfv[n] = *(const bf16x8*)&Bs[wc * 64 + n * 16 + fr][g * 8];
    #pragma unroll
    for (int m = 0; m < 4; ++m)
      #pragma unroll
      for (int n = 0; n < 4; ++n)
        acc[m][n] = __builtin_amdgcn_mfma_f32_16x16x32_bf16(af[m], bfv[n],
                                                            acc[m][n], 0, 0, 0);
  }
  #pragma unroll
  for (int m = 0; m < 4; ++m)
    #pragma unroll
    for (int n = 0; n < 4; ++n)
      #pragma unroll
      for (int r = 0; r < 4; ++r) {
        int row = row0 + wr * 64 + m * 16 + g * 4 + r;
        int col = col0 + wc * 64 + n * 16 + fr;
        float val = acc[m][n][r];
        if constexpr (MODE == 2) {
          ((bf16_t*)Cout)[(size_t)row * N + col] = (bf16_t)val;
        } else {
          val += R[(size_t)row * N + col];
          ((float*)Cout)[(size_t)row * N + col] = val;
        }
      }
}

// ------------------------------------------------------- flash attention -----
// grid (S/64, H). Block: 4 waves; wave w handles q rows qb*64+w*16 .. +15.
__global__ __launch_bounds__(256, 2) void attn_kernel(
    const bf16_t* __restrict__ q, const bf16_t* __restrict__ k,
    const bf16_t* __restrict__ v, bf16_t* __restrict__ o) {
  int h = blockIdx.y;
  int qb = blockIdx.x;
  int kvh = h >> 2;  // H/KVH = 4
  int wid = threadIdx.x >> 6, lane = threadIdx.x & 63;
  int g = lane >> 4, fr = lane & 15;

  __shared__ __align__(16) bf16_t k_lds[64][136];
  __shared__ __align__(16) bf16_t vt_lds[128][72];
  __shared__ __align__(16) bf16_t p_lds[4][16][72];

  int q0w = qb * 64 + wid * 16;
  bf16x8 q_frag[4];
  const bf16_t* qptr = q + ((size_t)(q0w + fr) * H_ + h) * DH_;
  #pragma unroll
  for (int kc = 0; kc < 4; ++kc)
    q_frag[kc] = *(const bf16x8*)(qptr + kc * 32 + g * 8);

  f32x4 o_frag[8] = {};
  float m_run[4], l_run[4];
  #pragma unroll
  for (int r = 0; r < 4; ++r) { m_run[r] = -1e30f; l_run[r] = 0.f; }

  const float sc = 0.08838834764831845f * 1.4426950408889634f;  // scale*log2e

  for (int t = 0; t <= qb; ++t) {
    int kv0 = t * 64;
    __syncthreads();  // prev-iter LDS reads done before overwrite
    for (int i = threadIdx.x; i < 1024; i += 256) {
      int row = i >> 4, c8 = (i & 15) * 8;
      size_t gofs = ((size_t)(kv0 + row) * KVH_ + kvh) * DH_ + c8;
      bf16x8 k8 = *(const bf16x8*)(k + gofs);
      *(bf16x8*)&k_lds[row][c8] = k8;
      bf16x8 v8 = *(const bf16x8*)(v + gofs);
      #pragma unroll
      for (int j = 0; j < 8; ++j) vt_lds[c8 + j][row] = v8[j];
    }
    __syncthreads();

    // S = Q @ K^T  (per wave: 16 q x 64 kv)
    f32x4 sfr[4];
    #pragma unroll
    for (int nf = 0; nf < 4; ++nf) {
      f32x4 acc = {};
      #pragma unroll
      for (int kc = 0; kc < 4; ++kc) {
        bf16x8 kf = *(const bf16x8*)&k_lds[fr + 16 * nf][kc * 32 + g * 8];
        acc = __builtin_amdgcn_mfma_f32_16x16x32_bf16(q_frag[kc], kf, acc, 0, 0, 0);
      }
      sfr[nf] = acc;
    }

    bool diag = (t == qb);
    float mtile[4];
    #pragma unroll
    for (int r = 0; r < 4; ++r) mtile[r] = -1e30f;
    #pragma unroll
    for (int nf = 0; nf < 4; ++nf)
      #pragma unroll
      for (int r = 0; r < 4; ++r) {
        if (diag) {
          int kvg = kv0 + nf * 16 + fr;
          int qg = q0w + 4 * g + r;
          if (kvg > qg) sfr[nf][r] = -1e30f;
        }
        mtile[r] = fmaxf(mtile[r], sfr[nf][r]);
      }
    #pragma unroll
    for (int r = 0; r < 4; ++r) {
      float mv = mtile[r];
      mv = fmaxf(mv, __shfl_xor(mv, 1));
      mv = fmaxf(mv, __shfl_xor(mv, 2));
      mv = fmaxf(mv, __shfl_xor(mv, 4));
      mv = fmaxf(mv, __shfl_xor(mv, 8));
      mtile[r] = mv;
    }
    float alpha[4];
    #pragma unroll
    for (int r = 0; r < 4; ++r) {
      float m_new = fmaxf(m_run[r], mtile[r]);
      alpha[r] = exp2f((m_run[r] - m_new) * sc);
      m_run[r] = m_new;
    }
    float lsum[4] = {0.f, 0.f, 0.f, 0.f};
    #pragma unroll
    for (int nf = 0; nf < 4; ++nf)
      #pragma unroll
      for (int r = 0; r < 4; ++r) {
        float p = exp2f((sfr[nf][r] - m_run[r]) * sc);
        sfr[nf][r] = p;
        lsum[r] += p;
      }
    #pragma unroll
    for (int r = 0; r < 4; ++r) {
      float lv = lsum[r];
      lv += __shfl_xor(lv, 1);
      lv += __shfl_xor(lv, 2);
      lv += __shfl_xor(lv, 4);
      lv += __shfl_xor(lv, 8);
      l_run[r] = l_run[r] * alpha[r] + lv;
    }
    #pragma unroll
    for (int nfo = 0; nfo < 8; ++nfo)
      #pragma unroll
      for (int r = 0; r < 4; ++r) o_frag[nfo][r] *= alpha[r];

    // P -> LDS in A-operand layout
    #pragma unroll
    for (int nf = 0; nf < 4; ++nf)
      #pragma unroll
      for (int r = 0; r < 4; ++r)
        p_lds[wid][4 * g + r][nf * 16 + fr] = (bf16_t)sfr[nf][r];
    __syncthreads();

    // O += P @ V
    #pragma unroll
    for (int kc = 0; kc < 2; ++kc) {
      bf16x8 pf = *(const bf16x8*)&p_lds[wid][fr][kc * 32 + g * 8];
      #pragma unroll
      for (int nfo = 0; nfo < 8; ++nfo) {
        bf16x8 vf = *(const bf16x8*)&vt_lds[nfo * 16 + fr][kc * 32 + g * 8];
        o_frag[nfo] = __builtin_amdgcn_mfma_f32_16x16x32_bf16(pf, vf, o_frag[nfo], 0, 0, 0);
      }
    }
  }

  #pragma unroll
  for (int nfo = 0; nfo < 8; ++nfo)
    #pragma unroll
    for (int r = 0; r < 4; ++r) {
      int qg = q0w + 4 * g + r;
      float val = o_frag[nfo][r] / l_run[r];
      o[((size_t)qg * H_ + h) * DH_ + nfo * 16 + fr] = (bf16_t)val;
    }
}

// -------------------------------------------------------------- SiLU*mul -----
__global__ __launch_bounds__(256) void silu_mul_kernel(
    const bf16_t* __restrict__ gin, const bf16_t* __restrict__ uin,
    bf16_t* __restrict__ hout, size_t n8) {
  size_t idx = (size_t)blockIdx.x * 256 + threadIdx.x;
  if (idx >= n8) return;
  bf16x8 g8 = *(const bf16x8*)(gin + idx * 8);
  bf16x8 u8 = *(const bf16x8*)(uin + idx * 8);
  bf16x8 h8;
  #pragma unroll
  for (int j = 0; j < 8; ++j) {
    float gv = (float)g8[j];
    float uv = (float)u8[j];
    float sv = gv / (1.f + __expf(-gv));
    h8[j] = (bf16_t)(sv * uv);
  }
  *(bf16x8*)(hout + idx * 8) = h8;
}

// ---------------------------------------------------------------- launch -----
extern "C" void kernel_launch(void* const* d_in, const int* in_sizes, int n_in,
                              void* d_out, int out_size, void* d_ws,
                              size_t ws_size, hipStream_t stream) {
  const float* x = (const float*)d_in[0];
  const int* pos = (const int*)d_in[1];
  const float* ln_w = (const float*)d_in[2];
  const float* ffln_w = (const float*)d_in[3];
  const float* wq = (const float*)d_in[4];
  const float* wk = (const float*)d_in[5];
  const float* wv = (const float*)d_in[6];
  const float* wo = (const float*)d_in[7];
  const float* wg = (const float*)d_in[8];
  const float* w1 = (const float*)d_in[9];
  const float* w2 = (const float*)d_in[10];

  char* ws = (char*)d_ws;
  size_t off = 0;
  auto alloc = [&](size_t bytes) {
    size_t o = off;
    off = (off + bytes + 255) & ~(size_t)255;
    return o;
  };
  bf16_t* a_bf  = (bf16_t*)(ws + alloc((size_t)S_ * D_ * 2));
  bf16_t* qb    = (bf16_t*)(ws + alloc((size_t)S_ * H_ * DH_ * 2));
  bf16_t* kb    = (bf16_t*)(ws + alloc((size_t)S_ * KVH_ * DH_ * 2));
  bf16_t* vb    = (bf16_t*)(ws + alloc((size_t)S_ * KVH_ * DH_ * 2));
  bf16_t* qr    = (bf16_t*)(ws + alloc((size_t)S_ * H_ * DH_ * 2));
  bf16_t* kr    = (bf16_t*)(ws + alloc((size_t)S_ * KVH_ * DH_ * 2));
  bf16_t* attnb = (bf16_t*)(ws + alloc((size_t)S_ * H_ * DH_ * 2));
  float*  x1    = (float*)(ws + alloc((size_t)S_ * D_ * 4));
  bf16_t* b_bf  = (bf16_t*)(ws + alloc((size_t)S_ * D_ * 2));
  bf16_t* g_bf  = (bf16_t*)(ws + alloc((size_t)S_ * HID_ * 2));
  bf16_t* u_bf  = (bf16_t*)(ws + alloc((size_t)S_ * HID_ * 2));
  bf16_t* h_bf  = (bf16_t*)(ws + alloc((size_t)S_ * HID_ * 2));
  float*  cos_t = (float*)(ws + alloc((size_t)S_ * 64 * 4));
  float*  sin_t = (float*)(ws + alloc((size_t)S_ * 64 * 4));

  // 1. a = rmsnorm(x, ln_w)
  rmsnorm_kernel<<<S_, 256, 0, stream>>>(x, ln_w, a_bf);
  // 2-4. q,k,v
  gemm_kernel<2><<<dim3(S_ / 128, D_ / 128), 256, 0, stream>>>(
      a_bf, wq, nullptr, qb, S_, H_ * DH_, D_);
  gemm_kernel<2><<<dim3(S_ / 128, (KVH_ * DH_) / 128), 256, 0, stream>>>(
      a_bf, wk, nullptr, kb, S_, KVH_ * DH_, D_);
  gemm_kernel<2><<<dim3(S_ / 128, (KVH_ * DH_) / 128), 256, 0, stream>>>(
      a_bf, wv, nullptr, vb, S_, KVH_ * DH_, D_);
  // 5. rope table
  rope_table_kernel<<<(S_ * 64) / 256, 256, 0, stream>>>(pos, cos_t, sin_t);
  // 6-7. rope q,k
  {
    int total_q = S_ * H_ * 64;
    rope_apply_kernel<<<(total_q + 255) / 256, 256, 0, stream>>>(
        qb, qr, cos_t, sin_t, H_, total_q);
    int total_k = S_ * KVH_ * 64;
    rope_apply_kernel<<<(total_k + 255) / 256, 256, 0, stream>>>(
        kb, kr, cos_t, sin_t, KVH_, total_k);
  }
  // 8. attention
  attn_kernel<<<dim3(S_ / 64, H_), 256, 0, stream>>>(qr, kr, vb, attnb);
  // 9. x1 = x + attn @ wo
  gemm_kernel<1><<<dim3(S_ / 128, D_ / 128), 256, 0, stream>>>(
      attnb, wo, x, x1, S_, D_, H_ * DH_);
  // 10. b = rmsnorm(x1, ffln_w)
  rmsnorm_kernel<<<S_, 256, 0, stream>>>(x1, ffln_w, b_bf);
  // 11-12. g, u
  gemm_kernel<2><<<dim3(S_ / 128, HID_ / 128), 256, 0, stream>>>(
      b_bf, wg, nullptr, g_bf, S_, HID_, D_);
  gemm_kernel<2><<<dim3(S_ / 128, HID_ / 128), 256, 0, stream>>>(
      b_bf, w1, nullptr, u_bf, S_, HID_, D_);
  // 13. h = silu(g) * u
  {
    size_t n8 = (size_t)S_ * HID_ / 8;
    silu_mul_kernel<<<(unsigned)((n8 + 255) / 256), 256, 0, stream>>>(
        g_bf, u_bf, h_bf, n8);
  }
  // 14. out = x1 + h @ w2
  gemm_kernel<1><<<dim3(S_ / 128, D_ / 128), 256, 0, stream>>>(
      h_bf, w2, x1, (float*)d_out, S_, D_, HID_);
}

// Round 2
// 1746.028 us; speedup vs baseline: 2.3359x; 2.3359x over previous
//
#include <hip/hip_runtime.h>
#include <hip/hip_bf16.h>

typedef __bf16 bf16_t;
typedef __bf16 bf16x4 __attribute__((ext_vector_type(4)));
typedef __bf16 bf16x8 __attribute__((ext_vector_type(8)));
typedef float f32x4 __attribute__((ext_vector_type(4)));

#define S_ 2048
#define D_ 4096
#define H_ 32
#define KVH_ 8
#define DH_ 128
#define HID_ 11008
#define QKV_N 6144   // 4096 q + 1024 k + 1024 v
#define GU_N 22016   // 11008 g + 11008 u

__device__ __forceinline__ void gl16(const bf16_t* g, bf16_t* l) {
  __builtin_amdgcn_global_load_lds(
      (const __attribute__((address_space(1))) unsigned int*)g,
      (__attribute__((address_space(3))) unsigned int*)l, 16, 0, 0);
}

// ---------------------------------------------------------------- RMSNorm ----
__global__ __launch_bounds__(256) void rmsnorm_kernel(
    const float* __restrict__ x, const float* __restrict__ w,
    bf16_t* __restrict__ out) {
  int row = blockIdx.x;
  const float* xr = x + (size_t)row * D_;
  float ss = 0.f;
  #pragma unroll
  for (int it = 0; it < 4; ++it) {
    int i = threadIdx.x * 4 + it * 1024;
    float4 v = *(const float4*)(xr + i);
    ss += v.x * v.x + v.y * v.y + v.z * v.z + v.w * v.w;
  }
  #pragma unroll
  for (int off = 32; off; off >>= 1) ss += __shfl_xor(ss, off);
  __shared__ float s4[4];
  if ((threadIdx.x & 63) == 0) s4[threadIdx.x >> 6] = ss;
  __syncthreads();
  float tot = s4[0] + s4[1] + s4[2] + s4[3];
  float rinv = rsqrtf(tot / (float)D_ + 1e-5f);
  bf16_t* orow = out + (size_t)row * D_;
  #pragma unroll
  for (int it = 0; it < 4; ++it) {
    int i = threadIdx.x * 4 + it * 1024;
    float4 v = *(const float4*)(xr + i);
    orow[i + 0] = (bf16_t)(v.x * rinv * w[i + 0]);
    orow[i + 1] = (bf16_t)(v.y * rinv * w[i + 1]);
    orow[i + 2] = (bf16_t)(v.z * rinv * w[i + 2]);
    orow[i + 3] = (bf16_t)(v.w * rinv * w[i + 3]);
  }
}

// ------------------------------------------- weight transpose f32 -> bf16 ----
// W [K][N] f32  ->  WT [N][K] bf16.  tile 32k x 256n per block.
__global__ __launch_bounds__(256) void wtrans_kernel(
    const float* __restrict__ W, bf16_t* __restrict__ WT, int K, int N) {
  __shared__ bf16_t t[32][264];
  int k0 = blockIdx.x * 32, n0 = blockIdx.y * 256;
  #pragma unroll
  for (int i = 0; i < 8; ++i) {
    int flat = i * 1024 + threadIdx.x * 4;
    int kk = flat >> 8, nn = flat & 255;
    float4 wv = *(const float4*)(W + (size_t)(k0 + kk) * N + n0 + nn);
    bf16_t* p = &t[kk][nn];
    p[0] = (bf16_t)wv.x; p[1] = (bf16_t)wv.y;
    p[2] = (bf16_t)wv.z; p[3] = (bf16_t)wv.w;
  }
  __syncthreads();
  #pragma unroll
  for (int i = 0; i < 8; ++i) {
    int nn = i * 32 + (threadIdx.x >> 3);
    int kc = (threadIdx.x & 7) * 4;
    bf16x4 vals;
    #pragma unroll
    for (int j = 0; j < 4; ++j) vals[j] = t[kc + j][nn];
    *(bf16x4*)(WT + (size_t)(n0 + nn) * K + k0 + kc) = vals;
  }
}

// ------------------------------------------------------------- RoPE table ----
__global__ __launch_bounds__(256) void rope_table_kernel(
    const int* __restrict__ pos_ids, float* __restrict__ cos_t,
    float* __restrict__ sin_t) {
  int idx = blockIdx.x * 256 + threadIdx.x;  // S_*64
  int s = idx >> 6, i = idx & 63;
  float pos = (float)pos_ids[s];
  float inv_freq = exp2f(-(float)i * (13.287712379549449f / 64.0f));
  float ang = pos * inv_freq;
  cos_t[idx] = cosf(ang);
  sin_t[idx] = sinf(ang);
}

// --------------------------------------------- RoPE in-place on qkv buffer ---
__global__ __launch_bounds__(256) void rope_kernel(
    bf16_t* __restrict__ buf, const float* __restrict__ cos_t,
    const float* __restrict__ sin_t, int nheads, int colbase, int total) {
  int idx = blockIdx.x * 256 + threadIdx.x;
  if (idx >= total) return;
  int i = idx & 63;
  int t2 = idx >> 6;
  int s = t2 / nheads, h = t2 % nheads;
  size_t base = (size_t)s * QKV_N + colbase + h * 128 + 2 * i;
  float x1 = (float)buf[base], x2 = (float)buf[base + 1];
  float c = cos_t[s * 64 + i], sn = sin_t[s * 64 + i];
  buf[base]     = (bf16_t)(x1 * c - x2 * sn);
  buf[base + 1] = (bf16_t)(x1 * sn + x2 * c);
}

// ------------------------------------------------------------------ GEMM -----
// C[M][N] = A[M][lda](bf16, K cols used) @ BT[N][K](bf16 row-major)
// MODE 0: bf16 out (ldc); MODE 1: f32 out = acc + R (ldc)
template <int MODE>
__global__ __launch_bounds__(256) void gemm_bt_kernel(
    const bf16_t* __restrict__ A, int lda, const bf16_t* __restrict__ BT,
    const float* __restrict__ R, void* __restrict__ Cout, int ldc, int N,
    int K) {
  __shared__ __align__(16) bf16_t As[128 * 32];
  __shared__ __align__(16) bf16_t Bs[128 * 32];
  int tid = threadIdx.x;
  int lane = tid & 63, wid = tid >> 6;
  int wr = wid >> 1, wc = wid & 1;
  int g = lane >> 4, fr = lane & 15;

  // XCD-aware swizzle (all grids have nwg % 8 == 0)
  int nwg = gridDim.x * gridDim.y;
  int orig = blockIdx.y * gridDim.x + blockIdx.x;
  int wg = (orig & 7) * (nwg >> 3) + (orig >> 3);
  int bx = wg % gridDim.x, by = wg / gridDim.x;
  int row0 = bx * 128, col0 = by * 128;

  int off0 = tid * 16;                     // byte offset into 8KB tile
  int r0 = off0 >> 6, ke = (off0 & 63) >> 1;  // row, k-elem within row
  const bf16_t* aSrc0 = A + (size_t)(row0 + r0) * lda + ke;
  const bf16_t* aSrc1 = A + (size_t)(row0 + r0 + 64) * lda + ke;
  const bf16_t* bSrc0 = BT + (size_t)(col0 + r0) * K + ke;
  const bf16_t* bSrc1 = BT + (size_t)(col0 + r0 + 64) * K + ke;
  bf16_t* aDst0 = &As[tid * 8];
  bf16_t* aDst1 = &As[2048 + tid * 8];
  bf16_t* bDst0 = &Bs[tid * 8];
  bf16_t* bDst1 = &Bs[2048 + tid * 8];

  f32x4 acc[4][4] = {};
  for (int k0 = 0; k0 < K; k0 += 32) {
    __syncthreads();
    gl16(aSrc0 + k0, aDst0);
    gl16(aSrc1 + k0, aDst1);
    gl16(bSrc0 + k0, bDst0);
    gl16(bSrc1 + k0, bDst1);
    __syncthreads();
    bf16x8 af[4], bfv[4];
    #pragma unroll
    for (int m = 0; m < 4; ++m)
      af[m] = *(const bf16x8*)&As[(wr * 64 + m * 16 + fr) * 32 + g * 8];
    #pragma unroll
    for (int n = 0; n < 4; ++n)
      bfv[n] = *(const bf16x8*)&Bs[(wc * 64 + n * 16 + fr) * 32 + g * 8];
    #pragma unroll
    for (int m = 0; m < 4; ++m)
      #pragma unroll
      for (int n = 0; n < 4; ++n)
        acc[m][n] = __builtin_amdgcn_mfma_f32_16x16x32_bf16(af[m], bfv[n],
                                                            acc[m][n], 0, 0, 0);
  }
  #pragma unroll
  for (int m = 0; m < 4; ++m)
    #pragma unroll
    for (int n = 0; n < 4; ++n)
      #pragma unroll
      for (int r = 0; r < 4; ++r) {
        int row = row0 + wr * 64 + m * 16 + g * 4 + r;
        int col = col0 + wc * 64 + n * 16 + fr;
        float val = acc[m][n][r];
        if constexpr (MODE == 0) {
          ((bf16_t*)Cout)[(size_t)row * ldc + col] = (bf16_t)val;
        } else {
          ((float*)Cout)[(size_t)row * ldc + col] =
              val + R[(size_t)row * ldc + col];
        }
      }
}

// ------------------------------------------------------- flash attention -----
// grid (S/64, H). 4 waves; wave w: q rows qb*64+w*16..+15. reads packed qkv.
__global__ __launch_bounds__(256) void attn_kernel(
    const bf16_t* __restrict__ qkv, bf16_t* __restrict__ o) {
  int h = blockIdx.y;
  int qb = blockIdx.x;
  int kvh = h >> 2;
  int wid = threadIdx.x >> 6, lane = threadIdx.x & 63;
  int g = lane >> 4, fr = lane & 15;

  __shared__ __align__(16) bf16_t k_lds[64][136];
  __shared__ __align__(16) bf16_t vt_lds[128][72];
  __shared__ __align__(16) bf16_t p_lds[4][16][72];

  int q0w = qb * 64 + wid * 16;
  bf16x8 q_frag[4];
  const bf16_t* qptr = qkv + (size_t)(q0w + fr) * QKV_N + h * 128;
  #pragma unroll
  for (int kc = 0; kc < 4; ++kc)
    q_frag[kc] = *(const bf16x8*)(qptr + kc * 32 + g * 8);

  f32x4 o_frag[8] = {};
  float m_run[4], l_run[4];
  #pragma unroll
  for (int r = 0; r < 4; ++r) { m_run[r] = -1e30f; l_run[r] = 0.f; }

  const float sc = 0.08838834764831845f * 1.4426950408889634f;

  for (int t = 0; t <= qb; ++t) {
    int kv0 = t * 64;
    __syncthreads();
    for (int i = threadIdx.x; i < 1024; i += 256) {
      int row = i >> 4, c8 = (i & 15) * 8;
      size_t base = (size_t)(kv0 + row) * QKV_N + kvh * 128 + c8;
      bf16x8 k8 = *(const bf16x8*)(qkv + base + 4096);
      *(bf16x8*)&k_lds[row][c8] = k8;
      bf16x8 v8 = *(const bf16x8*)(qkv + base + 5120);
      #pragma unroll
      for (int j = 0; j < 8; ++j) vt_lds[c8 + j][row] = v8[j];
    }
    __syncthreads();

    f32x4 sfr[4];
    #pragma unroll
    for (int nf = 0; nf < 4; ++nf) {
      f32x4 acc = {};
      #pragma unroll
      for (int kc = 0; kc < 4; ++kc) {
        bf16x8 kf = *(const bf16x8*)&k_lds[fr + 16 * nf][kc * 32 + g * 8];
        acc = __builtin_amdgcn_mfma_f32_16x16x32_bf16(q_frag[kc], kf, acc, 0, 0, 0);
      }
      sfr[nf] = acc;
    }

    bool diag = (t == qb);
    float mtile[4];
    #pragma unroll
    for (int r = 0; r < 4; ++r) mtile[r] = -1e30f;
    #pragma unroll
    for (int nf = 0; nf < 4; ++nf)
      #pragma unroll
      for (int r = 0; r < 4; ++r) {
        if (diag) {
          int kvg = kv0 + nf * 16 + fr;
          int qg = q0w + 4 * g + r;
          if (kvg > qg) sfr[nf][r] = -1e30f;
        }
        mtile[r] = fmaxf(mtile[r], sfr[nf][r]);
      }
    #pragma unroll
    for (int r = 0; r < 4; ++r) {
      float mv = mtile[r];
      mv = fmaxf(mv, __shfl_xor(mv, 1));
      mv = fmaxf(mv, __shfl_xor(mv, 2));
      mv = fmaxf(mv, __shfl_xor(mv, 4));
      mv = fmaxf(mv, __shfl_xor(mv, 8));
      mtile[r] = mv;
    }
    float alpha[4];
    #pragma unroll
    for (int r = 0; r < 4; ++r) {
      float m_new = fmaxf(m_run[r], mtile[r]);
      alpha[r] = exp2f((m_run[r] - m_new) * sc);
      m_run[r] = m_new;
    }
    float lsum[4] = {0.f, 0.f, 0.f, 0.f};
    #pragma unroll
    for (int nf = 0; nf < 4; ++nf)
      #pragma unroll
      for (int r = 0; r < 4; ++r) {
        float p = exp2f((sfr[nf][r] - m_run[r]) * sc);
        sfr[nf][r] = p;
        lsum[r] += p;
      }
    #pragma unroll
    for (int r = 0; r < 4; ++r) {
      float lv = lsum[r];
      lv += __shfl_xor(lv, 1);
      lv += __shfl_xor(lv, 2);
      lv += __shfl_xor(lv, 4);
      lv += __shfl_xor(lv, 8);
      l_run[r] = l_run[r] * alpha[r] + lv;
    }
    #pragma unroll
    for (int nfo = 0; nfo < 8; ++nfo)
      #pragma unroll
      for (int r = 0; r < 4; ++r) o_frag[nfo][r] *= alpha[r];

    #pragma unroll
    for (int nf = 0; nf < 4; ++nf)
      #pragma unroll
      for (int r = 0; r < 4; ++r)
        p_lds[wid][4 * g + r][nf * 16 + fr] = (bf16_t)sfr[nf][r];
    __syncthreads();

    #pragma unroll
    for (int kc = 0; kc < 2; ++kc) {
      bf16x8 pf = *(const bf16x8*)&p_lds[wid][fr][kc * 32 + g * 8];
      #pragma unroll
      for (int nfo = 0; nfo < 8; ++nfo) {
        bf16x8 vf = *(const bf16x8*)&vt_lds[nfo * 16 + fr][kc * 32 + g * 8];
        o_frag[nfo] = __builtin_amdgcn_mfma_f32_16x16x32_bf16(pf, vf, o_frag[nfo], 0, 0, 0);
      }
    }
  }

  #pragma unroll
  for (int nfo = 0; nfo < 8; ++nfo)
    #pragma unroll
    for (int r = 0; r < 4; ++r) {
      int qg = q0w + 4 * g + r;
      float val = o_frag[nfo][r] / l_run[r];
      o[(size_t)qg * (H_ * DH_) + h * DH_ + nfo * 16 + fr] = (bf16_t)val;
    }
}

// ---------------------------------------------- SiLU*mul in-place on gu ------
__global__ __launch_bounds__(256) void silu_mul_kernel(bf16_t* __restrict__ gu) {
  size_t idx = (size_t)blockIdx.x * 256 + threadIdx.x;  // S*HID/8
  int r = (int)(idx / (HID_ / 8));
  int c8 = (int)(idx % (HID_ / 8));
  bf16_t* p = gu + (size_t)r * GU_N + c8 * 8;
  bf16x8 g8 = *(const bf16x8*)p;
  bf16x8 u8 = *(const bf16x8*)(p + HID_);
  bf16x8 h8;
  #pragma unroll
  for (int j = 0; j < 8; ++j) {
    float gv = (float)g8[j];
    float uv = (float)u8[j];
    h8[j] = (bf16_t)(gv / (1.f + __expf(-gv)) * uv);
  }
  *(bf16x8*)p = h8;
}

// ---------------------------------------------------------------- launch -----
extern "C" void kernel_launch(void* const* d_in, const int* in_sizes, int n_in,
                              void* d_out, int out_size, void* d_ws,
                              size_t ws_size, hipStream_t stream) {
  const float* x = (const float*)d_in[0];
  const int* pos = (const int*)d_in[1];
  const float* ln_w = (const float*)d_in[2];
  const float* ffln_w = (const float*)d_in[3];
  const float* wq = (const float*)d_in[4];
  const float* wk = (const float*)d_in[5];
  const float* wv = (const float*)d_in[6];
  const float* wo = (const float*)d_in[7];
  const float* wg = (const float*)d_in[8];
  const float* w1 = (const float*)d_in[9];
  const float* w2 = (const float*)d_in[10];

  char* ws = (char*)d_ws;
  size_t off = 0;
  auto alloc = [&](size_t bytes) {
    size_t o = off;
    off = (off + bytes + 255) & ~(size_t)255;
    return o;
  };
  bf16_t* Wbuf = (bf16_t*)(ws + alloc((size_t)GU_N * D_ * 2));  // 180MB shared
  bf16_t* nbuf = (bf16_t*)(ws + alloc((size_t)S_ * D_ * 2));    // a / attn / b
  bf16_t* qkv  = (bf16_t*)(ws + alloc((size_t)S_ * QKV_N * 2));
  float*  x1   = (float*)(ws + alloc((size_t)S_ * D_ * 4));
  bf16_t* gu   = (bf16_t*)(ws + alloc((size_t)S_ * GU_N * 2));
  float*  cos_t = (float*)(ws + alloc((size_t)S_ * 64 * 4));
  float*  sin_t = (float*)(ws + alloc((size_t)S_ * 64 * 4));

  // 1. a = rmsnorm(x)
  rmsnorm_kernel<<<S_, 256, 0, stream>>>(x, ln_w, nbuf);
  // 2. W_qkv^T (bf16) : rows 0..4095=wq^T, 4096..5119=wk^T, 5120..6143=wv^T
  wtrans_kernel<<<dim3(D_ / 32, D_ / 256), 256, 0, stream>>>(wq, Wbuf, D_, D_);
  wtrans_kernel<<<dim3(D_ / 32, 1024 / 256), 256, 0, stream>>>(
      wk, Wbuf + (size_t)4096 * D_, D_, 1024);
  wtrans_kernel<<<dim3(D_ / 32, 1024 / 256), 256, 0, stream>>>(
      wv, Wbuf + (size_t)5120 * D_, D_, 1024);
  rope_table_kernel<<<(S_ * 64) / 256, 256, 0, stream>>>(pos, cos_t, sin_t);
  // 3. qkv = a @ Wqkv
  gemm_bt_kernel<0><<<dim3(S_ / 128, QKV_N / 128), 256, 0, stream>>>(
      nbuf, D_, Wbuf, nullptr, qkv, QKV_N, QKV_N, D_);
  // 4. rope q,k in-place
  rope_kernel<<<(S_ * H_ * 64) / 256, 256, 0, stream>>>(
      qkv, cos_t, sin_t, H_, 0, S_ * H_ * 64);
  rope_kernel<<<(S_ * KVH_ * 64) / 256, 256, 0, stream>>>(
      qkv, cos_t, sin_t, KVH_, 4096, S_ * KVH_ * 64);
  // 5. attention -> nbuf
  attn_kernel<<<dim3(S_ / 64, H_), 256, 0, stream>>>(qkv, nbuf);
  // 6. x1 = x + attn @ wo
  wtrans_kernel<<<dim3(D_ / 32, D_ / 256), 256, 0, stream>>>(wo, Wbuf, D_, D_);
  gemm_bt_kernel<1><<<dim3(S_ / 128, D_ / 128), 256, 0, stream>>>(
      nbuf, D_, Wbuf, x, x1, D_, D_, D_);
  // 7. b = rmsnorm(x1)
  rmsnorm_kernel<<<S_, 256, 0, stream>>>(x1, ffln_w, nbuf);
  // 8. gu = b @ [wg|w1]
  wtrans_kernel<<<dim3(D_ / 32, HID_ / 256), 256, 0, stream>>>(wg, Wbuf, D_, HID_);
  wtrans_kernel<<<dim3(D_ / 32, HID_ / 256), 256, 0, stream>>>(
      w1, Wbuf + (size_t)HID_ * D_, D_, HID_);
  gemm_bt_kernel<0><<<dim3(S_ / 128, GU_N / 128), 256, 0, stream>>>(
      nbuf, D_, Wbuf, nullptr, gu, GU_N, GU_N, D_);
  // 9. h = silu(g)*u in-place (left half of gu)
  silu_mul_kernel<<<(S_ * HID_ / 8) / 256, 256, 0, stream>>>(gu);
  // 10. out = x1 + h @ w2
  wtrans_kernel<<<dim3(HID_ / 32, D_ / 256), 256, 0, stream>>>(w2, Wbuf, HID_, D_);
  gemm_bt_kernel<1><<<dim3(S_ / 128, D_ / 128), 256, 0, stream>>>(
      gu, GU_N, Wbuf, x1, (float*)d_out, D_, D_, HID_);
}

// Round 4
// 1435.265 us; speedup vs baseline: 2.8417x; 1.2165x over previous
//
#include <hip/hip_runtime.h>
#include <hip/hip_bf16.h>

typedef __bf16 bf16_t;
typedef __bf16 bf16x4 __attribute__((ext_vector_type(4)));
typedef __bf16 bf16x8 __attribute__((ext_vector_type(8)));
typedef float f32x4 __attribute__((ext_vector_type(4)));

#define S_ 2048
#define D_ 4096
#define H_ 32
#define KVH_ 8
#define DH_ 128
#define HID_ 11008
#define QKV_N 6144   // 4096 q + 1024 k + 1024 v
#define GU_N 22016   // 11008 g + 11008 u

__device__ __forceinline__ void gl16(const bf16_t* g, bf16_t* l) {
  __builtin_amdgcn_global_load_lds(
      (const __attribute__((address_space(1))) unsigned int*)g,
      (__attribute__((address_space(3))) unsigned int*)l, 16, 0, 0);
}

// ---------------------------------------------------------------- RMSNorm ----
__global__ __launch_bounds__(256) void rmsnorm_kernel(
    const float* __restrict__ x, const float* __restrict__ w,
    bf16_t* __restrict__ out) {
  int row = blockIdx.x;
  const float* xr = x + (size_t)row * D_;
  float ss = 0.f;
  #pragma unroll
  for (int it = 0; it < 4; ++it) {
    int i = threadIdx.x * 4 + it * 1024;
    float4 v = *(const float4*)(xr + i);
    ss += v.x * v.x + v.y * v.y + v.z * v.z + v.w * v.w;
  }
  #pragma unroll
  for (int off = 32; off; off >>= 1) ss += __shfl_xor(ss, off);
  __shared__ float s4[4];
  if ((threadIdx.x & 63) == 0) s4[threadIdx.x >> 6] = ss;
  __syncthreads();
  float tot = s4[0] + s4[1] + s4[2] + s4[3];
  float rinv = rsqrtf(tot / (float)D_ + 1e-5f);
  bf16_t* orow = out + (size_t)row * D_;
  #pragma unroll
  for (int it = 0; it < 4; ++it) {
    int i = threadIdx.x * 4 + it * 1024;
    float4 v = *(const float4*)(xr + i);
    orow[i + 0] = (bf16_t)(v.x * rinv * w[i + 0]);
    orow[i + 1] = (bf16_t)(v.y * rinv * w[i + 1]);
    orow[i + 2] = (bf16_t)(v.z * rinv * w[i + 2]);
    orow[i + 3] = (bf16_t)(v.w * rinv * w[i + 3]);
  }
}

// ----------------------- combine wo-partials + residual + RMSNorm ------------
// x1 = x + p0 + p1 ; out = rmsnorm(x1) * w   (one row per block)
__global__ __launch_bounds__(256) void combine_rms_kernel(
    const float* __restrict__ x, const float* __restrict__ p0,
    const float* __restrict__ p1, const float* __restrict__ w,
    float* __restrict__ x1, bf16_t* __restrict__ out) {
  int row = blockIdx.x;
  size_t base = (size_t)row * D_;
  float ss = 0.f;
  float4 vals[4];
  #pragma unroll
  for (int it = 0; it < 4; ++it) {
    int i = threadIdx.x * 4 + it * 1024;
    float4 a = *(const float4*)(x + base + i);
    float4 b = *(const float4*)(p0 + base + i);
    float4 c = *(const float4*)(p1 + base + i);
    float4 v;
    v.x = a.x + b.x + c.x; v.y = a.y + b.y + c.y;
    v.z = a.z + b.z + c.z; v.w = a.w + b.w + c.w;
    vals[it] = v;
    *(float4*)(x1 + base + i) = v;
    ss += v.x * v.x + v.y * v.y + v.z * v.z + v.w * v.w;
  }
  #pragma unroll
  for (int off = 32; off; off >>= 1) ss += __shfl_xor(ss, off);
  __shared__ float s4[4];
  if ((threadIdx.x & 63) == 0) s4[threadIdx.x >> 6] = ss;
  __syncthreads();
  float tot = s4[0] + s4[1] + s4[2] + s4[3];
  float rinv = rsqrtf(tot / (float)D_ + 1e-5f);
  #pragma unroll
  for (int it = 0; it < 4; ++it) {
    int i = threadIdx.x * 4 + it * 1024;
    float4 v = vals[it];
    out[base + i + 0] = (bf16_t)(v.x * rinv * w[i + 0]);
    out[base + i + 1] = (bf16_t)(v.y * rinv * w[i + 1]);
    out[base + i + 2] = (bf16_t)(v.z * rinv * w[i + 2]);
    out[base + i + 3] = (bf16_t)(v.w * rinv * w[i + 3]);
  }
}

// ----------------------------- combine w2-partials + residual -> d_out -------
__global__ __launch_bounds__(256) void combine_out_kernel(
    const float* __restrict__ x1, const float* __restrict__ p0,
    const float* __restrict__ p1, float* __restrict__ outp) {
  size_t i = ((size_t)blockIdx.x * 256 + threadIdx.x) * 4;
  float4 a = *(const float4*)(x1 + i);
  float4 b = *(const float4*)(p0 + i);
  float4 c = *(const float4*)(p1 + i);
  float4 v;
  v.x = a.x + b.x + c.x; v.y = a.y + b.y + c.y;
  v.z = a.z + b.z + c.z; v.w = a.w + b.w + c.w;
  *(float4*)(outp + i) = v;
}

// ------------------------------------------- weight transpose f32 -> bf16 ----
__global__ __launch_bounds__(256) void wtrans_kernel(
    const float* __restrict__ W, bf16_t* __restrict__ WT, int K, int N) {
  __shared__ bf16_t t[32][264];
  int k0 = blockIdx.x * 32, n0 = blockIdx.y * 256;
  #pragma unroll
  for (int i = 0; i < 8; ++i) {
    int flat = i * 1024 + threadIdx.x * 4;
    int kk = flat >> 8, nn = flat & 255;
    float4 wv = *(const float4*)(W + (size_t)(k0 + kk) * N + n0 + nn);
    bf16_t* p = &t[kk][nn];
    p[0] = (bf16_t)wv.x; p[1] = (bf16_t)wv.y;
    p[2] = (bf16_t)wv.z; p[3] = (bf16_t)wv.w;
  }
  __syncthreads();
  #pragma unroll
  for (int i = 0; i < 8; ++i) {
    int nn = i * 32 + (threadIdx.x >> 3);
    int kc = (threadIdx.x & 7) * 4;
    bf16x4 vals;
    #pragma unroll
    for (int j = 0; j < 4; ++j) vals[j] = t[kc + j][nn];
    *(bf16x4*)(WT + (size_t)(n0 + nn) * K + k0 + kc) = vals;
  }
}

// ------------------------------------------------------------- RoPE table ----
__global__ __launch_bounds__(256) void rope_table_kernel(
    const int* __restrict__ pos_ids, float* __restrict__ cos_t,
    float* __restrict__ sin_t) {
  int idx = blockIdx.x * 256 + threadIdx.x;  // S_*64
  int s = idx >> 6, i = idx & 63;
  float pos = (float)pos_ids[s];
  float inv_freq = exp2f(-(float)i * (13.287712379549449f / 64.0f));
  float ang = pos * inv_freq;
  cos_t[idx] = cosf(ang);
  sin_t[idx] = sinf(ang);
}

// --------------------------------------------- RoPE in-place on qkv buffer ---
__global__ __launch_bounds__(256) void rope_kernel(
    bf16_t* __restrict__ buf, const float* __restrict__ cos_t,
    const float* __restrict__ sin_t, int nheads, int colbase, int total) {
  int idx = blockIdx.x * 256 + threadIdx.x;
  if (idx >= total) return;
  int i = idx & 63;
  int t2 = idx >> 6;
  int s = t2 / nheads, h = t2 % nheads;
  size_t base = (size_t)s * QKV_N + colbase + h * 128 + 2 * i;
  float x1 = (float)buf[base], x2 = (float)buf[base + 1];
  float c = cos_t[s * 64 + i], sn = sin_t[s * 64 + i];
  buf[base]     = (bf16_t)(x1 * c - x2 * sn);
  buf[base + 1] = (bf16_t)(x1 * sn + x2 * c);
}

// ------------------------------------------------------- 256x256 GEMM --------
// C[2048][N] = A[2048][K+] (bf16) @ BT[N][K+] (bf16)
// MODE 0: bf16 out; MODE 2: f32 plain store.
// SPLIT 1: grid doubled; high half of (swizzled) blocks takes K-offset K and
//          writes to partial buffer 1 (Cout + 2048*ldc floats).
// 8 waves (2Mx4N), BK=64, 2 K-tiles double-buffered, 4 phases/K-tile,
// counted vmcnt(8), conflict-free [kk][row][32] LDS.

#define VMW(N)                                          \
  asm volatile("s_waitcnt vmcnt(" #N ")" ::: "memory"); \
  __builtin_amdgcn_sched_barrier(0)

#define DO_PHASE(BI, KK, MH, DO_LDB, STAGE1, STAGE2, WAITCODE)             \
  {                                                                        \
    _Pragma("unroll") for (int m = 0; m < 4; ++m)                          \
      aF[m] = *(const bf16x8*)&lds[BI][0][wr][KK]                          \
          [((MH) * 64 + m * 16 + fr) * 32 + g * 8];                        \
    if (DO_LDB) {                                                          \
      _Pragma("unroll") for (int n = 0; n < 4; ++n)                        \
        bF[n] = *(const bf16x8*)&lds[BI][1][wcH][KK]                       \
            [(wcL * 64 + n * 16 + fr) * 32 + g * 8];                       \
    }                                                                      \
    STAGE1;                                                                \
    STAGE2;                                                                \
    asm volatile("" ::: "memory");                                         \
    __builtin_amdgcn_s_barrier();                                          \
    asm volatile("s_waitcnt lgkmcnt(0)" ::: "memory");                     \
    __builtin_amdgcn_sched_barrier(0);                                     \
    __builtin_amdgcn_s_setprio(1);                                         \
    _Pragma("unroll") for (int m = 0; m < 4; ++m)                          \
      _Pragma("unroll") for (int n = 0; n < 4; ++n)                        \
        acc[(MH) * 4 + m][n] = __builtin_amdgcn_mfma_f32_16x16x32_bf16(    \
            aF[m], bF[n], acc[(MH) * 4 + m][n], 0, 0, 0);                  \
    __builtin_amdgcn_s_setprio(0);                                         \
    __builtin_amdgcn_sched_barrier(0);                                     \
    WAITCODE;                                                              \
    asm volatile("" ::: "memory");                                         \
    __builtin_amdgcn_s_barrier();                                          \
    asm volatile("" ::: "memory");                                         \
  }

#define DO_TILE(BI, T)                                                     \
  {                                                                        \
    const int Tp1 = (T) + 1 < NT, Tp2 = (T) + 2 < NT;                      \
    DO_PHASE(BI, 0, 0, 1,                                                  \
             if (Tp1) stage(BI ^ 1, 0, 0, 1, (T) + 1),                     \
             if (Tp1) stage(BI ^ 1, 1, 0, 1, (T) + 1), );                  \
    DO_PHASE(BI, 0, 1, 0,                                                  \
             if (Tp1) stage(BI ^ 1, 0, 1, 1, (T) + 1),                     \
             if (Tp1) stage(BI ^ 1, 1, 1, 1, (T) + 1),                     \
             if (Tp1) { VMW(8); } else { VMW(0); });                       \
    DO_PHASE(BI, 1, 0, 1,                                                  \
             if (Tp2) stage(BI, 0, 0, 0, (T) + 2),                         \
             if (Tp2) stage(BI, 1, 0, 0, (T) + 2), );                      \
    DO_PHASE(BI, 1, 1, 0,                                                  \
             if (Tp2) stage(BI, 0, 1, 0, (T) + 2),                         \
             if (Tp2) stage(BI, 1, 1, 0, (T) + 2),                         \
             if (Tp2) { VMW(8); } else if (Tp1) { VMW(4); });              \
  }

template <int MODE, int SPLIT>
__global__ __launch_bounds__(512, 2) void gemm256_kernel(
    const bf16_t* __restrict__ A, int lda, const bf16_t* __restrict__ BT,
    int ldb, void* __restrict__ Cout, int ldc, int K) {
  // [buf][A=0/B=1][half(row-block)][kk][128 rows * 32 elems]  = 128 KiB
  __shared__ __align__(16) bf16_t lds[2][2][2][2][128 * 32];

  const int tid = threadIdx.x;
  const int lane = tid & 63;
  const int wid = tid >> 6;
  const int wr = wid >> 2;            // 0..1  (M half)
  const int wc = wid & 3;             // 0..3  (N quarter)
  const int wcH = wc >> 1, wcL = wc & 1;
  const int g = lane >> 4, fr = lane & 15;

  // XCD-aware bijective swizzle (grid % 8 == 0 for all launches)
  const int nwg = gridDim.x;
  const int orig = blockIdx.x;
  int wg = (orig & 7) * (nwg >> 3) + (orig >> 3);
  int kz = 0;
  if constexpr (SPLIT) {
    const int half = nwg >> 1;
    kz = wg >= half;
    wg -= kz * half;
  }
  const int bx = wg & 7;              // M blocks = 2048/256 = 8
  const int by = wg >> 3;
  const size_t row0 = (size_t)bx * 256, col0 = (size_t)by * 256;

  const size_t lda2 = (size_t)lda * 2, ldb2 = (size_t)ldb * 2;
  const size_t kzoff = (size_t)kz * K * 2;
  const char* aB0 =
      (const char*)A + (row0 + (tid >> 2)) * lda2 + (tid & 3) * 16 + kzoff;
  const char* aB1 = aB0 + (size_t)128 * lda2;
  const char* bB0 =
      (const char*)BT + (col0 + (tid >> 2)) * ldb2 + (tid & 3) * 16 + kzoff;
  const char* bB1 = bB0 + (size_t)128 * ldb2;

  auto stage = [&](int bi, int ab, int h, int kk, int kt) {
    const char* base = ab ? (h ? bB1 : bB0) : (h ? aB1 : aB0);
    gl16((const bf16_t*)(base + (size_t)kt * 128 + kk * 64),
         &lds[bi][ab][h][kk][tid * 8]);
  };

  f32x4 acc[8][4] = {};
  bf16x8 aF[4], bF[4];
  const int NT = K / 64;  // even for all our shapes

  // prologue: tile0 fully, tile1 kk0
  stage(0, 0, 0, 0, 0); stage(0, 1, 0, 0, 0);
  stage(0, 0, 1, 0, 0); stage(0, 1, 1, 0, 0);
  stage(0, 0, 0, 1, 0); stage(0, 1, 0, 1, 0);
  stage(0, 0, 1, 1, 0); stage(0, 1, 1, 1, 0);
  stage(1, 0, 0, 0, 1); stage(1, 1, 0, 0, 1);
  stage(1, 0, 1, 0, 1); stage(1, 1, 1, 0, 1);
  VMW(4);
  asm volatile("" ::: "memory");
  __builtin_amdgcn_s_barrier();
  asm volatile("" ::: "memory");

  for (int T = 0; T < NT; T += 2) {
    DO_TILE(0, T);
    DO_TILE(1, T + 1);
  }

  // epilogue
  float* fOut = (float*)Cout + (size_t)kz * 2048 * ldc;
  #pragma unroll
  for (int mf = 0; mf < 8; ++mf)
    #pragma unroll
    for (int n = 0; n < 4; ++n)
      #pragma unroll
      for (int r = 0; r < 4; ++r) {
        size_t row = row0 + wr * 128 + mf * 16 + g * 4 + r;
        size_t col = col0 + wc * 64 + n * 16 + fr;
        float val = acc[mf][n][r];
        if constexpr (MODE == 0) {
          ((bf16_t*)Cout)[row * ldc + col] = (bf16_t)val;
        } else {
          fOut[row * ldc + col] = val;
        }
      }
}

// ------------------------------------------------------- flash attention -----
__global__ __launch_bounds__(256) void attn_kernel(
    const bf16_t* __restrict__ qkv, bf16_t* __restrict__ o) {
  int h = blockIdx.y;
  int qb = blockIdx.x;
  int kvh = h >> 2;
  int wid = threadIdx.x >> 6, lane = threadIdx.x & 63;
  int g = lane >> 4, fr = lane & 15;

  __shared__ __align__(16) bf16_t k_lds[64][136];
  __shared__ __align__(16) bf16_t vt_lds[128][72];
  __shared__ __align__(16) bf16_t p_lds[4][16][72];

  int q0w = qb * 64 + wid * 16;
  bf16x8 q_frag[4];
  const bf16_t* qptr = qkv + (size_t)(q0w + fr) * QKV_N + h * 128;
  #pragma unroll
  for (int kc = 0; kc < 4; ++kc)
    q_frag[kc] = *(const bf16x8*)(qptr + kc * 32 + g * 8);

  f32x4 o_frag[8] = {};
  float m_run[4], l_run[4];
  #pragma unroll
  for (int r = 0; r < 4; ++r) { m_run[r] = -1e30f; l_run[r] = 0.f; }

  const float sc = 0.08838834764831845f * 1.4426950408889634f;

  for (int t = 0; t <= qb; ++t) {
    int kv0 = t * 64;
    __syncthreads();
    for (int i = threadIdx.x; i < 1024; i += 256) {
      int row = i >> 4, c8 = (i & 15) * 8;
      size_t base = (size_t)(kv0 + row) * QKV_N + kvh * 128 + c8;
      bf16x8 k8 = *(const bf16x8*)(qkv + base + 4096);
      *(bf16x8*)&k_lds[row][c8] = k8;
      bf16x8 v8 = *(const bf16x8*)(qkv + base + 5120);
      #pragma unroll
      for (int j = 0; j < 8; ++j) vt_lds[c8 + j][row] = v8[j];
    }
    __syncthreads();

    f32x4 sfr[4];
    #pragma unroll
    for (int nf = 0; nf < 4; ++nf) {
      f32x4 acc = {};
      #pragma unroll
      for (int kc = 0; kc < 4; ++kc) {
        bf16x8 kf = *(const bf16x8*)&k_lds[fr + 16 * nf][kc * 32 + g * 8];
        acc = __builtin_amdgcn_mfma_f32_16x16x32_bf16(q_frag[kc], kf, acc, 0, 0, 0);
      }
      sfr[nf] = acc;
    }

    bool diag = (t == qb);
    float mtile[4];
    #pragma unroll
    for (int r = 0; r < 4; ++r) mtile[r] = -1e30f;
    #pragma unroll
    for (int nf = 0; nf < 4; ++nf)
      #pragma unroll
      for (int r = 0; r < 4; ++r) {
        if (diag) {
          int kvg = kv0 + nf * 16 + fr;
          int qg = q0w + 4 * g + r;
          if (kvg > qg) sfr[nf][r] = -1e30f;
        }
        mtile[r] = fmaxf(mtile[r], sfr[nf][r]);
      }
    #pragma unroll
    for (int r = 0; r < 4; ++r) {
      float mv = mtile[r];
      mv = fmaxf(mv, __shfl_xor(mv, 1));
      mv = fmaxf(mv, __shfl_xor(mv, 2));
      mv = fmaxf(mv, __shfl_xor(mv, 4));
      mv = fmaxf(mv, __shfl_xor(mv, 8));
      mtile[r] = mv;
    }
    float alpha[4];
    #pragma unroll
    for (int r = 0; r < 4; ++r) {
      float m_new = fmaxf(m_run[r], mtile[r]);
      alpha[r] = exp2f((m_run[r] - m_new) * sc);
      m_run[r] = m_new;
    }
    float lsum[4] = {0.f, 0.f, 0.f, 0.f};
    #pragma unroll
    for (int nf = 0; nf < 4; ++nf)
      #pragma unroll
      for (int r = 0; r < 4; ++r) {
        float p = exp2f((sfr[nf][r] - m_run[r]) * sc);
        sfr[nf][r] = p;
        lsum[r] += p;
      }
    #pragma unroll
    for (int r = 0; r < 4; ++r) {
      float lv = lsum[r];
      lv += __shfl_xor(lv, 1);
      lv += __shfl_xor(lv, 2);
      lv += __shfl_xor(lv, 4);
      lv += __shfl_xor(lv, 8);
      l_run[r] = l_run[r] * alpha[r] + lv;
    }
    #pragma unroll
    for (int nfo = 0; nfo < 8; ++nfo)
      #pragma unroll
      for (int r = 0; r < 4; ++r) o_frag[nfo][r] *= alpha[r];

    #pragma unroll
    for (int nf = 0; nf < 4; ++nf)
      #pragma unroll
      for (int r = 0; r < 4; ++r)
        p_lds[wid][4 * g + r][nf * 16 + fr] = (bf16_t)sfr[nf][r];
    __syncthreads();

    #pragma unroll
    for (int kc = 0; kc < 2; ++kc) {
      bf16x8 pf = *(const bf16x8*)&p_lds[wid][fr][kc * 32 + g * 8];
      #pragma unroll
      for (int nfo = 0; nfo < 8; ++nfo) {
        bf16x8 vf = *(const bf16x8*)&vt_lds[nfo * 16 + fr][kc * 32 + g * 8];
        o_frag[nfo] = __builtin_amdgcn_mfma_f32_16x16x32_bf16(pf, vf, o_frag[nfo], 0, 0, 0);
      }
    }
  }

  #pragma unroll
  for (int nfo = 0; nfo < 8; ++nfo)
    #pragma unroll
    for (int r = 0; r < 4; ++r) {
      int qg = q0w + 4 * g + r;
      float val = o_frag[nfo][r] / l_run[r];
      o[(size_t)qg * (H_ * DH_) + h * DH_ + nfo * 16 + fr] = (bf16_t)val;
    }
}

// ---------------------------------------------- SiLU*mul in-place on gu ------
__global__ __launch_bounds__(256) void silu_mul_kernel(bf16_t* __restrict__ gu) {
  size_t idx = (size_t)blockIdx.x * 256 + threadIdx.x;  // S*HID/8
  int r = (int)(idx / (HID_ / 8));
  int c8 = (int)(idx % (HID_ / 8));
  bf16_t* p = gu + (size_t)r * GU_N + c8 * 8;
  bf16x8 g8 = *(const bf16x8*)p;
  bf16x8 u8 = *(const bf16x8*)(p + HID_);
  bf16x8 h8;
  #pragma unroll
  for (int j = 0; j < 8; ++j) {
    float gv = (float)g8[j];
    float uv = (float)u8[j];
    h8[j] = (bf16_t)(gv / (1.f + __expf(-gv)) * uv);
  }
  *(bf16x8*)p = h8;
}

// ---------------------------------------------------------------- launch -----
extern "C" void kernel_launch(void* const* d_in, const int* in_sizes, int n_in,
                              void* d_out, int out_size, void* d_ws,
                              size_t ws_size, hipStream_t stream) {
  const float* x = (const float*)d_in[0];
  const int* pos = (const int*)d_in[1];
  const float* ln_w = (const float*)d_in[2];
  const float* ffln_w = (const float*)d_in[3];
  const float* wq = (const float*)d_in[4];
  const float* wk = (const float*)d_in[5];
  const float* wv = (const float*)d_in[6];
  const float* wo = (const float*)d_in[7];
  const float* wg = (const float*)d_in[8];
  const float* w1 = (const float*)d_in[9];
  const float* w2 = (const float*)d_in[10];

  char* ws = (char*)d_ws;
  size_t off = 0;
  auto alloc = [&](size_t bytes) {
    size_t o = off;
    off = (off + bytes + 255) & ~(size_t)255;
    return o;
  };
  bf16_t* Wbuf = (bf16_t*)(ws + alloc((size_t)GU_N * D_ * 2));  // ~172MB shared
  bf16_t* nbuf = (bf16_t*)(ws + alloc((size_t)S_ * D_ * 2));    // a / attn / b
  bf16_t* qkv  = (bf16_t*)(ws + alloc((size_t)S_ * QKV_N * 2));
  float*  x1   = (float*)(ws + alloc((size_t)S_ * D_ * 4));
  bf16_t* gu   = (bf16_t*)(ws + alloc((size_t)S_ * GU_N * 2));
  float*  cos_t = (float*)(ws + alloc((size_t)S_ * 64 * 4));
  float*  sin_t = (float*)(ws + alloc((size_t)S_ * 64 * 4));
  // split-K partial buffers live in the unused tail of Wbuf:
  // weights occupy at most 96MB (w2^T = 90MB); partials at +96MB..+160MB.
  float* part = (float*)((char*)Wbuf + ((size_t)96 << 20));  // 2 x 32MB

  // 1. a = rmsnorm(x)
  rmsnorm_kernel<<<S_, 256, 0, stream>>>(x, ln_w, nbuf);
  // 2. W_qkv^T (bf16): rows 0..4095=wq^T, 4096..5119=wk^T, 5120..6143=wv^T
  wtrans_kernel<<<dim3(D_ / 32, D_ / 256), 256, 0, stream>>>(wq, Wbuf, D_, D_);
  wtrans_kernel<<<dim3(D_ / 32, 1024 / 256), 256, 0, stream>>>(
      wk, Wbuf + (size_t)4096 * D_, D_, 1024);
  wtrans_kernel<<<dim3(D_ / 32, 1024 / 256), 256, 0, stream>>>(
      wv, Wbuf + (size_t)5120 * D_, D_, 1024);
  rope_table_kernel<<<(S_ * 64) / 256, 256, 0, stream>>>(pos, cos_t, sin_t);
  // 3. qkv = a @ Wqkv   (grid 8x24 = 192)
  gemm256_kernel<0, 0><<<dim3((S_ / 256) * (QKV_N / 256)), 512, 0, stream>>>(
      nbuf, D_, Wbuf, D_, qkv, QKV_N, D_);
  // 4. rope q,k in-place
  rope_kernel<<<(S_ * H_ * 64) / 256, 256, 0, stream>>>(
      qkv, cos_t, sin_t, H_, 0, S_ * H_ * 64);
  rope_kernel<<<(S_ * KVH_ * 64) / 256, 256, 0, stream>>>(
      qkv, cos_t, sin_t, KVH_, 4096, S_ * KVH_ * 64);
  // 5. attention -> nbuf
  attn_kernel<<<dim3(S_ / 64, H_), 256, 0, stream>>>(qkv, nbuf);
  // 6. partials = attn @ wo (split-K 2x2048, 256 blocks)
  wtrans_kernel<<<dim3(D_ / 32, D_ / 256), 256, 0, stream>>>(wo, Wbuf, D_, D_);
  gemm256_kernel<2, 1><<<dim3((S_ / 256) * (D_ / 256) * 2), 512, 0, stream>>>(
      nbuf, D_, Wbuf, D_, part, D_, 2048);
  // 7. x1 = x + p0 + p1 ; b = rmsnorm(x1)
  combine_rms_kernel<<<S_, 256, 0, stream>>>(
      x, part, part + (size_t)S_ * D_, ffln_w, x1, nbuf);
  // 8. gu = b @ [wg|w1]   (grid 8x86 = 688)
  wtrans_kernel<<<dim3(D_ / 32, HID_ / 256), 256, 0, stream>>>(wg, Wbuf, D_, HID_);
  wtrans_kernel<<<dim3(D_ / 32, HID_ / 256), 256, 0, stream>>>(
      w1, Wbuf + (size_t)HID_ * D_, D_, HID_);
  gemm256_kernel<0, 0><<<dim3((S_ / 256) * (GU_N / 256)), 512, 0, stream>>>(
      nbuf, D_, Wbuf, D_, gu, GU_N, D_);
  // 9. h = silu(g)*u in-place (left half of gu)
  silu_mul_kernel<<<(S_ * HID_ / 8) / 256, 256, 0, stream>>>(gu);
  // 10. partials = h @ w2 (split-K 2x5504, 256 blocks)
  wtrans_kernel<<<dim3(HID_ / 32, D_ / 256), 256, 0, stream>>>(w2, Wbuf, HID_, D_);
  gemm256_kernel<2, 1><<<dim3((S_ / 256) * (D_ / 256) * 2), 512, 0, stream>>>(
      gu, GU_N, Wbuf, HID_, part, D_, 5504);
  // 11. out = x1 + p0 + p1
  combine_out_kernel<<<(S_ * D_ / 4) / 256, 256, 0, stream>>>(
      x1, part, part + (size_t)S_ * D_, (float*)d_out);
}